// Round 7
// baseline (1605.666 us; speedup 1.0000x reference)
//
#include <hip/hip_runtime.h>
#include <hip/hip_bf16.h>

typedef _Float16 f16;
typedef __attribute__((ext_vector_type(8))) _Float16 f16x8;
typedef __attribute__((ext_vector_type(2))) _Float16 f16x2;
typedef __attribute__((ext_vector_type(4))) float f32x4;

constexpr int CB = 64, CP = 196, CH = 512, CV = 30000, CVP = 30080, CT = 20;

__device__ __forceinline__ float sigf(float x) { return 1.f / (1.f + __expf(-x)); }

#if defined(__has_builtin)
#if __has_builtin(__builtin_amdgcn_fdot2)
#define HAVE_FDOT2 1
#endif
#endif

__device__ __forceinline__ f16x2 asf16x2(unsigned u) {
    union { unsigned x; f16x2 h; } c; c.x = u; return c.h;
}
__device__ __forceinline__ float dotp(f16x2 a, f16x2 b, float c) {
#ifdef HAVE_FDOT2
    return __builtin_amdgcn_fdot2(a, b, c, false);
#else
    return fmaf((float)a[0], (float)b[0], fmaf((float)a[1], (float)b[1], c));
#endif
}

// ---------------------------------------------------------------------------
// mega convert/transpose/prep kernel (one-time prologue)
// Weight layouts for the per-batch matvec loop (paired-K, output-major):
//   WdaT[kk][o][2]  : o in 0..1023 (att2 cols 0-511 = W_da, gate cols = W_fb)
//   Bp  [kk][c][2]  : c = 4*d + g  (gate g of h-dim d), K = [xawe(512); h(512)]
//   WihE_p[c][512]  : rows = permuted cols c for the embIH GEMM
// ---------------------------------------------------------------------------
__device__ __forceinline__ void cvt8(const float* __restrict__ s, f16* __restrict__ d) {
    float4 a = *(const float4*)s;
    float4 b = *(const float4*)(s + 4);
    f16x8 o;
    o[0] = (f16)a.x; o[1] = (f16)a.y; o[2] = (f16)a.z; o[3] = (f16)a.w;
    o[4] = (f16)b.x; o[5] = (f16)b.y; o[6] = (f16)b.z; o[7] = (f16)b.w;
    *(f16x8*)d = o;
}

__global__ __launch_bounds__(256) void k_mega(
    const float* __restrict__ enc, const float* __restrict__ W_ea,
    const float* __restrict__ W_da, const float* __restrict__ W_fb,
    const float* __restrict__ W_ih, const float* __restrict__ W_hh,
    const float* __restrict__ W_fc, const float* __restrict__ emb,
    const int* __restrict__ caps, const float* __restrict__ b_da,
    const float* __restrict__ b_fb, const float* __restrict__ b_ih,
    const float* __restrict__ b_hh,
    f16* __restrict__ enc_h, f16* __restrict__ Wea_h, f16* __restrict__ WdaT,
    f16* __restrict__ Bp, f16* __restrict__ WihE_p, f16* __restrict__ Wfc_h,
    f16* __restrict__ embg, float* __restrict__ bcat, float* __restrict__ bsum_p)
{
    constexpr long long E0 = 802816;            // enc cvt (12544*512/8)
    constexpr long long E1 = E0 + 32768;        // W_ea
    constexpr long long E2 = E1 + 1920000;      // W_fc
    constexpr long long E3 = E2 + 5120;         // Wfc pad zeros
    constexpr long long E4 = E3 + 81920;        // emb gather
    constexpr long long E5 = E4 + 65536;        // WdaT paired-K  (kk 256 x oq 256)
    constexpr long long E6 = E5 + 262144;       // Bp paired-K    (kk 512 x cq 512)
    constexpr long long E7 = E6 + 131072;       // WihE_p         (c 2048 x 64)
    constexpr long long TOT = E7 + 3072;        // biases

    for (long long id = (long long)blockIdx.x * 256 + threadIdx.x; id < TOT;
         id += (long long)gridDim.x * 256) {
        if (id < E0) {
            cvt8(enc + id * 8, enc_h + id * 8);
        } else if (id < E1) {
            long long c = id - E0; cvt8(W_ea + c * 8, Wea_h + c * 8);
        } else if (id < E2) {
            long long c = id - E1; cvt8(W_fc + c * 8, Wfc_h + c * 8);
        } else if (id < E3) {
            long long c = id - E2; f16x8 z = {};
            *(f16x8*)&Wfc_h[15360000 + c * 8] = z;
        } else if (id < E4) {
            long long c = id - E3; int m = (int)(c >> 6), j = (int)(c & 63);
            int tt = m >> 6, bb = m & 63;
            int row = caps[bb * 21 + tt];
            cvt8(emb + (size_t)row * 512 + j * 8, embg + (size_t)m * 512 + j * 8);
        } else if (id < E5) {
            long long c = id - E4;
            int kk = (int)(c >> 8), oq = (int)(c & 255), o0 = oq * 4;
            f16x8 o;
#pragma unroll
            for (int d = 0; d < 4; ++d) {
                int oo = o0 + d;
                const float* src = (oo < 512) ? (W_da + (size_t)oo * 512)
                                              : (W_fb + (size_t)(oo - 512) * 512);
                o[2 * d]     = (f16)src[2 * kk];
                o[2 * d + 1] = (f16)src[2 * kk + 1];
            }
            *(f16x8*)&WdaT[(size_t)kk * 2048 + oq * 8] = o;
        } else if (id < E6) {
            long long c = id - E5;
            int kk = (int)(c >> 9), cq = (int)(c & 511);
            f16x8 o;
#pragma unroll
            for (int g = 0; g < 4; ++g) {
                int r = g * 512 + cq;   // orig gate row
#pragma unroll
                for (int j = 0; j < 2; ++j) {
                    int k = 2 * kk + j;
                    float v = (k < 512) ? W_ih[(size_t)r * 1024 + 512 + k]
                                        : W_hh[(size_t)r * 512 + (k - 512)];
                    o[2 * g + j] = (f16)v;
                }
            }
            *(f16x8*)&Bp[(size_t)kk * 4096 + cq * 8] = o;
        } else if (id < E7) {
            long long c = id - E6;
            int cc = (int)(c >> 6), j8 = (int)(c & 63);
            int r = (cc & 3) * 512 + (cc >> 2);
            cvt8(W_ih + (size_t)r * 1024 + j8 * 8, WihE_p + (size_t)cc * 512 + j8 * 8);
        } else {
            int i = (int)(id - E7);
            if (i < 512) bcat[i] = b_da[i];
            else if (i < 1024) bcat[i] = b_fb[i - 512];
            else {
                int cc = i - 1024;
                int r = (cc & 3) * 512 + (cc >> 2);
                bsum_p[cc] = b_ih[r] + b_hh[r];
            }
        }
    }
}

// h0 = mean_p(enc) -> hbuf slot 0 (f16) and cinit (f32)
__global__ __launch_bounds__(256) void k_h0(const float* __restrict__ enc,
                                            f16* __restrict__ hbuf, float* __restrict__ cinit)
{
    int b = blockIdx.x;
    for (int h = threadIdx.x; h < CH; h += 256) {
        const float* p = enc + (size_t)b * CP * CH + h;
        float s = 0.f;
        for (int q = 0; q < CP; ++q) s += p[q * CH];
        s *= (1.f / 196.f);
        hbuf[b * CH + h] = (f16)s;
        cinit[b * CH + h] = s;
    }
}

// ---------------------------------------------------------------------------
// K=512 GEMM (prologue + preds): tile 128x128, BK=32, padded LDS, reg prefetch
// ---------------------------------------------------------------------------
enum { EPI_F16B = 0, EPI_F32B = 1, EPI_PREDS = 2 };

template <int EPI>
__global__ __launch_bounds__(256) void gemm_k512(
    const f16* __restrict__ Aptr, const f16* __restrict__ Bptr, int N,
    const float* __restrict__ bias, float* __restrict__ Cf,
    f16* __restrict__ Ch, const int* __restrict__ lengths)
{
    constexpr int LD = 40;
    const int tid = threadIdx.x;
    const int lane = tid & 63, wave = tid >> 6;
    const int wr = wave >> 1, wc = wave & 1;
    const int bx = (EPI == EPI_PREDS) ? blockIdx.y : blockIdx.x;
    const int by = (EPI == EPI_PREDS) ? blockIdx.x : blockIdx.y;

    __shared__ f16 As[128 * LD];
    __shared__ f16 Bs[128 * LD];

    const f16* Ag = Aptr + (size_t)by * 128 * 512;
    const f16* Bg = Bptr + (size_t)bx * 128 * 512;

    int srow[2], skc[2];
#pragma unroll
    for (int i = 0; i < 2; ++i) { int ci = tid + i * 256; srow[i] = ci >> 2; skc[i] = (ci & 3) * 8; }

    f32x4 acc[4][4] = {};
    f16x8 ar[2], br[2];
#pragma unroll
    for (int i = 0; i < 2; ++i) {
        ar[i] = *(const f16x8*)&Ag[(size_t)srow[i] * 512 + skc[i]];
        br[i] = *(const f16x8*)&Bg[(size_t)srow[i] * 512 + skc[i]];
    }

    const int rr = lane & 15, kg = (lane >> 4) * 8;
    for (int kt = 0; kt < 16; ++kt) {
        __syncthreads();
#pragma unroll
        for (int i = 0; i < 2; ++i) {
            *(f16x8*)&As[srow[i] * LD + skc[i]] = ar[i];
            *(f16x8*)&Bs[srow[i] * LD + skc[i]] = br[i];
        }
        __syncthreads();
        if (kt < 15) {
            int k0 = (kt + 1) * 32;
#pragma unroll
            for (int i = 0; i < 2; ++i) {
                ar[i] = *(const f16x8*)&Ag[(size_t)srow[i] * 512 + k0 + skc[i]];
                br[i] = *(const f16x8*)&Bg[(size_t)srow[i] * 512 + k0 + skc[i]];
            }
        }
        f16x8 af[4], bf[4];
#pragma unroll
        for (int mi = 0; mi < 4; ++mi) af[mi] = *(const f16x8*)&As[(wr * 64 + mi * 16 + rr) * LD + kg];
#pragma unroll
        for (int ni = 0; ni < 4; ++ni) bf[ni] = *(const f16x8*)&Bs[(wc * 64 + ni * 16 + rr) * LD + kg];
#pragma unroll
        for (int mi = 0; mi < 4; ++mi)
#pragma unroll
            for (int ni = 0; ni < 4; ++ni)
                acc[mi][ni] = __builtin_amdgcn_mfma_f32_16x16x32_f16(af[mi], bf[ni], acc[mi][ni], 0, 0, 0);
    }

    const int m0 = by * 128 + wr * 64;
    const int n0 = bx * 128 + wc * 64;
    const int r0 = (lane >> 4) * 4, cc = lane & 15;
#pragma unroll
    for (int mi = 0; mi < 4; ++mi) {
#pragma unroll
        for (int ni = 0; ni < 4; ++ni) {
#pragma unroll
            for (int r = 0; r < 4; ++r) {
                int m = m0 + mi * 16 + r0 + r;
                int n = n0 + ni * 16 + cc;
                float v = acc[mi][ni][r];
                if constexpr (EPI == EPI_F16B) {
                    Ch[(size_t)m * N + n] = (f16)(v + bias[n]);
                } else if constexpr (EPI == EPI_F32B) {
                    Cf[(size_t)m * N + n] = v + bias[n];
                } else {
                    if (n < CV) {
                        int tt = m >> 6, b = m & 63;
                        float val = ((lengths[b] - 1) > tt) ? (v + bias[n]) : 0.f;
                        __builtin_nontemporal_store(val, &Cf[(size_t)b * (CT * CV) + (size_t)tt * CV + n]);
                    }
                }
            }
        }
    }
}

// ---------------------------------------------------------------------------
// Per-batch recurrence: 64 independent blocks (one per batch), 512 threads.
// ZERO inter-block sync. h, c, att2, xh all live in LDS for 20 steps.
// Matvecs via v_dot2_f32_f16 on paired-K transposed weights (coalesced).
// ---------------------------------------------------------------------------
__global__ __launch_bounds__(512) void k_batch(
    const f16* __restrict__ att1, const f16* __restrict__ ench,
    const f16* __restrict__ WdaT, const f16* __restrict__ Bp,
    const float* __restrict__ embIH, const float* __restrict__ Wfa,
    const float* __restrict__ bfa, const float* __restrict__ bcat,
    const int* __restrict__ lens, const float* __restrict__ cinit,
    f16* __restrict__ hbuf, float* __restrict__ alph)
{
    const int b = blockIdx.x, tid = threadIdx.x;
    const int lane = tid & 63, wv = tid >> 6;

    __shared__ f16 h_s[512];
    __shared__ float c_s[512];
    __shared__ f16 a2_s[1024];          // att2(0..511) + gate-arg(512..1023)
    __shared__ f16 xh_s[1024];          // [xawe(512); h(512)]
    __shared__ float es[200], als[200], red[16];
    __shared__ float awp[8][512];

    // persistent per-block state init
    h_s[tid] = hbuf[b * 512 + tid];
    c_s[tid] = cinit[b * 512 + tid];

    const float bfa0 = bfa[0];
    const int lb = lens[b];
    const float bc0 = bcat[2 * tid], bc1 = bcat[2 * tid + 1];
    f16x2 wf2[4];
#pragma unroll
    for (int j = 0; j < 4; ++j) {
        float2 w2 = *(const float2*)&Wfa[lane * 8 + 2 * j];
        wf2[j][0] = (f16)w2.x; wf2[j][1] = (f16)w2.y;
    }
    __syncthreads();

    for (int t = 0; t < CT; ++t) {
        // ---- stage 1: att2+gate matvec (out=1024, K=512; 2 outputs/thread) ----
        {
            float a0 = 0.f, a1 = 0.f;
            const f16* wbase = WdaT + 4 * tid;
            for (int kk4 = 0; kk4 < 64; ++kk4) {
                uint4 xv = *(const uint4*)&h_s[kk4 * 8];     // broadcast
                unsigned xw[4] = {xv.x, xv.y, xv.z, xv.w};
                const f16* wp = wbase + (size_t)kk4 * 4 * 2048;
#pragma unroll
                for (int u = 0; u < 4; ++u) {
                    uint2 wd = *(const uint2*)(wp + (size_t)u * 2048);
                    f16x2 xp = asf16x2(xw[u]);
                    a0 = dotp(asf16x2(wd.x), xp, a0);
                    a1 = dotp(asf16x2(wd.y), xp, a1);
                }
            }
            f16x2 o; o[0] = (f16)(a0 + bc0); o[1] = (f16)(a1 + bc1);
            *(f16x2*)&a2_s[2 * tid] = o;
        }
        __syncthreads();

        // ---- stage 2: e[p] = Wfa . relu(att1[b,p,:] + att2) + bfa ----
        {
            uint4 a2v = *(const uint4*)&a2_s[lane * 8];
            unsigned a2w[4] = {a2v.x, a2v.y, a2v.z, a2v.w};
            for (int p = wv; p < CP; p += 8) {
                uint4 av = *(const uint4*)&att1[((size_t)b * CP + p) * 512 + lane * 8];
                unsigned aw4[4] = {av.x, av.y, av.z, av.w};
                float eacc = 0.f;
#pragma unroll
                for (int j = 0; j < 4; ++j) {
                    f16x2 s = asf16x2(aw4[j]) + asf16x2(a2w[j]);
                    f16x2 r;
                    r[0] = (s[0] < (f16)0) ? (f16)0 : s[0];
                    r[1] = (s[1] < (f16)0) ? (f16)0 : s[1];
                    eacc = dotp(r, wf2[j], eacc);
                }
#pragma unroll
                for (int o = 32; o; o >>= 1) eacc += __shfl_down(eacc, o);
                if (lane == 0) es[p] = eacc + bfa0;
            }
        }
        __syncthreads();

        // ---- stage 3: softmax over 196 ----
        {
            float ev = (tid < CP) ? es[tid] : -1e30f;
            float mx = ev;
#pragma unroll
            for (int o = 32; o; o >>= 1) mx = fmaxf(mx, __shfl_down(mx, o));
            if (lane == 0) red[wv] = mx;
            __syncthreads();
            mx = red[0];
#pragma unroll
            for (int w = 1; w < 8; ++w) mx = fmaxf(mx, red[w]);
            float ex = (tid < CP) ? __expf(ev - mx) : 0.f;
            float sm = ex;
#pragma unroll
            for (int o = 32; o; o >>= 1) sm += __shfl_down(sm, o);
            if (lane == 0) red[8 + wv] = sm;
            __syncthreads();
            sm = red[8];
#pragma unroll
            for (int w = 1; w < 8; ++w) sm += red[8 + w];
            float al = ex / sm;
            if (tid < CP) {
                als[tid] = al;
                alph[(size_t)b * (CT * CP) + t * CP + tid] = ((lb - 1) > t) ? al : 0.f;
            }
        }
        __syncthreads();

        // ---- stage 4: awe (wave-split p, lane owns 8 h-dims) + gate + xh ----
        {
            float aw[8] = {};
            for (int p = wv; p < CP; p += 8) {
                float a = als[p];
                uint4 ev = *(const uint4*)&ench[((size_t)b * CP + p) * 512 + lane * 8];
                unsigned ew[4] = {ev.x, ev.y, ev.z, ev.w};
#pragma unroll
                for (int j = 0; j < 4; ++j) {
                    f16x2 e2 = asf16x2(ew[j]);
                    aw[2 * j]     = fmaf(a, (float)e2[0], aw[2 * j]);
                    aw[2 * j + 1] = fmaf(a, (float)e2[1], aw[2 * j + 1]);
                }
            }
#pragma unroll
            for (int j = 0; j < 8; ++j) awp[wv][lane * 8 + j] = aw[j];
            __syncthreads();
            float s = 0.f;
#pragma unroll
            for (int w = 0; w < 8; ++w) s += awp[w][tid];
            float gate = sigf((float)a2_s[512 + tid]);
            xh_s[tid] = (f16)(gate * s);
            xh_s[512 + tid] = h_s[tid];
        }
        __syncthreads();

        // ---- stage 5: gates matvec (out=2048, K=1024; 4 outputs/thread) + cell ----
        {
            float g0 = 0.f, g1 = 0.f, g2 = 0.f, g3 = 0.f;
            const f16* wbase = Bp + 8 * tid;
            for (int kk4 = 0; kk4 < 128; ++kk4) {
                uint4 xv = *(const uint4*)&xh_s[kk4 * 8];    // broadcast
                unsigned xw[4] = {xv.x, xv.y, xv.z, xv.w};
                const f16* wp = wbase + (size_t)kk4 * 4 * 4096;
#pragma unroll
                for (int u = 0; u < 4; ++u) {
                    uint4 wd = *(const uint4*)(wp + (size_t)u * 4096);
                    f16x2 xp = asf16x2(xw[u]);
                    g0 = dotp(asf16x2(wd.x), xp, g0);
                    g1 = dotp(asf16x2(wd.y), xp, g1);
                    g2 = dotp(asf16x2(wd.z), xp, g2);
                    g3 = dotp(asf16x2(wd.w), xp, g3);
                }
            }
            float4 ei = *(const float4*)&embIH[(size_t)(t * 64 + b) * 2048 + 4 * tid];
            float gi = g0 + ei.x, gf = g1 + ei.y, gg = g2 + ei.z, go = g3 + ei.w;
            float cn = sigf(gf) * c_s[tid] + sigf(gi) * tanhf(gg);
            float hn = sigf(go) * tanhf(cn);
            __syncthreads();   // all xh_s/h_s readers done before overwrite
            c_s[tid] = cn;
            h_s[tid] = (f16)hn;
            hbuf[(size_t)(t + 1) * 32768 + b * 512 + tid] = (f16)hn;
        }
        __syncthreads();
    }
}

// ---------------------------------------------------------------------------
extern "C" void kernel_launch(void* const* d_in, const int* in_sizes, int n_in,
                              void* d_out, int out_size, void* d_ws, size_t ws_size,
                              hipStream_t stream)
{
    const float* enc  = (const float*)d_in[0];
    const int*   caps = (const int*)d_in[1];
    const int*   lens = (const int*)d_in[2];
    const float* emb  = (const float*)d_in[3];
    const float* W_ea = (const float*)d_in[4];
    const float* b_ea = (const float*)d_in[5];
    const float* W_da = (const float*)d_in[6];
    const float* b_da = (const float*)d_in[7];
    const float* W_fa = (const float*)d_in[8];
    const float* b_fa = (const float*)d_in[9];
    const float* W_fb = (const float*)d_in[10];
    const float* b_fb = (const float*)d_in[11];
    const float* W_ih = (const float*)d_in[12];
    const float* W_hh = (const float*)d_in[13];
    const float* b_ih = (const float*)d_in[14];
    const float* b_hh = (const float*)d_in[15];
    const float* W_fc = (const float*)d_in[16];
    const float* b_fc = (const float*)d_in[17];

    float* out = (float*)d_out;
    float* alph_out = out + (size_t)CB * CT * CV;

    char* p = (char*)d_ws;
    auto carve = [&](size_t bytes) {
        char* r = p;
        p += (bytes + 255) & ~(size_t)255;
        return r;
    };
    f16* enc_h   = (f16*)carve((size_t)12544 * 512 * 2);
    f16* att1_h  = (f16*)carve((size_t)12544 * 512 * 2);
    f16* Wea_h   = (f16*)carve((size_t)512 * 512 * 2);
    f16* WdaT    = (f16*)carve((size_t)256 * 1024 * 2 * 2);   // [kk][1024][2]
    f16* Bp      = (f16*)carve((size_t)512 * 2048 * 2 * 2);   // [kk][2048][2]
    f16* WihE_p  = (f16*)carve((size_t)2048 * 512 * 2);
    f16* Wfc_h   = (f16*)carve((size_t)CVP * 512 * 2);
    f16* embg    = (f16*)carve((size_t)1280 * 512 * 2);
    float* embIH = (float*)carve((size_t)1280 * 2048 * 4);
    float* bcat  = (float*)carve(1024 * 4);
    float* bsum_p= (float*)carve(2048 * 4);
    f16* hbuf    = (f16*)carve((size_t)21 * 64 * 512 * 2);
    float* cinit = (float*)carve((size_t)64 * 512 * 4);

    hipLaunchKernelGGL(k_mega, dim3(4096), dim3(256), 0, stream,
                       enc, W_ea, W_da, W_fb, W_ih, W_hh, W_fc, emb, caps,
                       b_da, b_fb, b_ih, b_hh,
                       enc_h, Wea_h, WdaT, Bp, WihE_p, Wfc_h, embg, bcat, bsum_p);

    hipLaunchKernelGGL(k_h0, dim3(64), dim3(256), 0, stream, enc, hbuf, cinit);

    // att1 = enc_h @ W_ea^T + b_ea  (M=12544, N=512) -> f16
    hipLaunchKernelGGL((gemm_k512<EPI_F16B>), dim3(4, 98), dim3(256), 0, stream,
                       enc_h, Wea_h, 512, b_ea, (float*)nullptr, att1_h, (const int*)nullptr);
    // embIH = embg @ WihE_p^T + bsum_p  (M=1280, N=2048 permuted c=4d+g) -> f32
    hipLaunchKernelGGL((gemm_k512<EPI_F32B>), dim3(16, 10), dim3(256), 0, stream,
                       embg, WihE_p, 2048, bsum_p, embIH, (f16*)nullptr, (const int*)nullptr);

    // 20-step recurrence: 64 independent per-batch blocks, zero inter-block sync
    hipLaunchKernelGGL(k_batch, dim3(64), dim3(512), 0, stream,
                       att1_h, enc_h, WdaT, Bp, embIH, W_fa, b_fa, bcat,
                       lens, cinit, hbuf, alph_out);

    // predictions = h(1..20) @ W_fc^T + b_fc, masked scatter
    hipLaunchKernelGGL((gemm_k512<EPI_PREDS>), dim3(10, CVP / 128), dim3(256), 0, stream,
                       hbuf + 32768, Wfc_h, CVP, b_fc, out, (f16*)nullptr, lens);
}